// Round 1
// 358.401 us; speedup vs baseline: 1.0519x; 1.0519x over previous
//
#include <hip/hip_runtime.h>

#define B_    256
#define N_    196
#define NP_   208      // 13*16 padded key/query count
#define VSTR_ 264      // Vt row stride in bf16 (264*2B = 132 dwords == 4 mod 32: low-conflict)
#define DIM_  384
#define H_    12
#define KD_   32
#define VD_   32
#define F_    1152
#define ROWS_ (B_ * N_)
#define SCALE_ 0.17677669529663687f
#define EPS_  1e-5f

typedef __bf16 bf16_t;
typedef __bf16 bf16x2 __attribute__((ext_vector_type(2)));
typedef __bf16 bf16x4 __attribute__((ext_vector_type(4)));
typedef __bf16 bf16x8 __attribute__((ext_vector_type(8)));
typedef float  f32x4  __attribute__((ext_vector_type(4)));

__device__ __forceinline__ f32x4 mfma16(bf16x8 a, bf16x8 b, f32x4 c) {
    return __builtin_amdgcn_mfma_f32_16x16x32_bf16(a, b, c, 0, 0, 0);
}

// async global->LDS, 16B per lane. LDS dest must be wave-uniform base + lane*16.
__device__ __forceinline__ void gl2lds(const bf16_t* g, bf16_t* l) {
    __builtin_amdgcn_global_load_lds(
        (const __attribute__((address_space(1))) void*)g,
        (__attribute__((address_space(3))) void*)l, 16, 0, 0);
}

// ---------------------------------------------------------------------------
// Weight fp32 -> bf16 convert (grid covers exactly n/4 threads' worth).
// ---------------------------------------------------------------------------
__global__ __launch_bounds__(256) void cvt_w(const float* __restrict__ src,
                                             bf16_t* __restrict__ dst) {
    const int i = (blockIdx.x * 256 + threadIdx.x) * 4;
    const float4 v = *(const float4*)(src + i);
    bf16x4 o = {(bf16_t)v.x, (bf16_t)v.y, (bf16_t)v.z, (bf16_t)v.w};
    *(bf16x4*)(dst + i) = o;
}

// ---------------------------------------------------------------------------
// LayerNorm: one wave per row, 4 rows per block. fp32 in -> bf16 out.
// ---------------------------------------------------------------------------
__global__ __launch_bounds__(256) void ln_kernel(const float* __restrict__ x,
                                                 const float* __restrict__ w,
                                                 const float* __restrict__ bvec,
                                                 bf16_t* __restrict__ xn) {
    const int lane = threadIdx.x & 63;
    const int row  = blockIdx.x * 4 + (threadIdx.x >> 6);
    const float* xr = x + (size_t)row * DIM_;
    const float4 a = *(const float4*)(xr + lane * 4);
    const float2 c = *(const float2*)(xr + 256 + lane * 2);
    float s  = a.x + a.y + a.z + a.w + c.x + c.y;
    float s2 = a.x*a.x + a.y*a.y + a.z*a.z + a.w*a.w + c.x*c.x + c.y*c.y;
    #pragma unroll
    for (int o = 32; o > 0; o >>= 1) {
        s  += __shfl_xor(s, o);
        s2 += __shfl_xor(s2, o);
    }
    const float mu = s * (1.f / 384.f);
    const float rs = rsqrtf(s2 * (1.f / 384.f) - mu * mu + EPS_);
    const float4 w4 = *(const float4*)(w + lane * 4);
    const float2 w2 = *(const float2*)(w + 256 + lane * 2);
    const float4 b4 = *(const float4*)(bvec + lane * 4);
    const float2 b2 = *(const float2*)(bvec + 256 + lane * 2);
    bf16_t* orow = xn + (size_t)row * DIM_;
    bf16x4 o4 = {(bf16_t)((a.x - mu) * rs * w4.x + b4.x),
                 (bf16_t)((a.y - mu) * rs * w4.y + b4.y),
                 (bf16_t)((a.z - mu) * rs * w4.z + b4.z),
                 (bf16_t)((a.w - mu) * rs * w4.w + b4.w)};
    *(bf16x4*)(orow + lane * 4) = o4;
    bf16x2 o2 = {(bf16_t)((c.x - mu) * rs * w2.x + b2.x),
                 (bf16_t)((c.y - mu) * rs * w2.y + b2.y)};
    *(bf16x2*)(orow + 256 + lane * 2) = o2;
}

// ---------------------------------------------------------------------------
// TRANSPOSED bias: biasT[h][m][q], both dims padded to 208.
// m >= 196 (padded keys) -> -1e30 so exp() kills them; q >= 196 -> -1e30
// (those query lanes are discarded at store time).
// ---------------------------------------------------------------------------
__global__ __launch_bounds__(256) void bias_gather(const float* __restrict__ biases,
                                                   const int* __restrict__ idxs,
                                                   bf16_t* __restrict__ biasT) {
    const int e = blockIdx.x * 256 + threadIdx.x;
    if (e >= H_ * NP_ * NP_) return;
    const int h = e / (NP_ * NP_);
    const int r = e % (NP_ * NP_);
    const int m = r / NP_;
    const int q = r % NP_;
    const float v = (m < N_ && q < N_) ? biases[h * N_ + idxs[q * N_ + m]] : -1e30f;
    biasT[e] = (bf16_t)v;
}

// ---------------------------------------------------------------------------
// MFMA GEMM (m97 recipe): C[M][Nout] = A[M][K] @ Wt[Nout][K]^T + bias.
// MFMA operands SWAPPED (mfma(Wt_frag, A_frag)) so each lane's C-fragment is
// 4 consecutive COLUMNS of one row -> vectorized bf16x4/float4 epilogue.
// ---------------------------------------------------------------------------
template <typename OutT>
__global__ __launch_bounds__(256) void gemm_mfma(const bf16_t* __restrict__ A,
                                                 const bf16_t* __restrict__ Wt,
                                                 const float* __restrict__ bias,
                                                 OutT* __restrict__ C,
                                                 int M, int Nout, int K) {
    __shared__ __align__(16) bf16_t As[128][32];
    __shared__ __align__(16) bf16_t Bs[128][32];
    const int tid  = threadIdx.x;
    const int lane = tid & 63;
    const int wv   = tid >> 6;
    const int ln   = lane & 15;
    const int ko   = lane >> 4;
    const int wr   = (wv >> 1) * 64;
    const int wc   = (wv & 1) * 64;
    const size_t bm = (size_t)blockIdx.x * 128;
    const size_t bn = (size_t)blockIdx.y * 128;

    // staging geometry: wave w stages rows [w*16, w*16+16) and +64 of each tile
    const int srow = wv * 16 + (lane >> 2);
    const int scol = (lane & 3) * 8;
    const bf16_t* gA0 = A  + (bm + srow) * K + scol;
    const bf16_t* gA1 = gA0 + (size_t)64 * K;
    const bf16_t* gB0 = Wt + (bn + srow) * K + scol;
    const bf16_t* gB1 = gB0 + (size_t)64 * K;
    bf16_t* lA0 = &As[srow][scol];
    bf16_t* lA1 = &As[srow + 64][scol];
    bf16_t* lB0 = &Bs[srow][scol];
    bf16_t* lB1 = &Bs[srow + 64][scol];

    f32x4 acc[4][4];
    #pragma unroll
    for (int i = 0; i < 4; i++)
        #pragma unroll
        for (int j = 0; j < 4; j++)
            acc[i][j] = (f32x4){0.f, 0.f, 0.f, 0.f};

    for (int k0 = 0; k0 < K; k0 += 32) {
        gl2lds(gA0 + k0, lA0);
        gl2lds(gA1 + k0, lA1);
        gl2lds(gB0 + k0, lB0);
        gl2lds(gB1 + k0, lB1);
        __syncthreads();
        bf16x8 af[4], bfr[4];
        #pragma unroll
        for (int i = 0; i < 4; i++)
            af[i] = *(const bf16x8*)&As[wr + i * 16 + ln][ko * 8];
        #pragma unroll
        for (int j = 0; j < 4; j++)
            bfr[j] = *(const bf16x8*)&Bs[wc + j * 16 + ln][ko * 8];
        #pragma unroll
        for (int i = 0; i < 4; i++)
            #pragma unroll
            for (int j = 0; j < 4; j++)
                acc[i][j] = mfma16(bfr[j], af[i], acc[i][j]);   // C^T fragment
        __syncthreads();
    }

    // epilogue: lane owns row (bm+wr+i*16+ln), cols (bn+wc+j*16+ko*4 .. +3)
    #pragma unroll
    for (int j = 0; j < 4; j++) {
        const int jc = wc + j * 16 + ko * 4;
        const float4 b4 = *(const float4*)(bias + bn + jc);
        #pragma unroll
        for (int i = 0; i < 4; i++) {
            const size_t row = bm + wr + i * 16 + ln;
            const float v0 = acc[i][j][0] + b4.x;
            const float v1 = acc[i][j][1] + b4.y;
            const float v2 = acc[i][j][2] + b4.z;
            const float v3 = acc[i][j][3] + b4.w;
            OutT* dst = C + row * (size_t)Nout + bn + jc;
            if constexpr (sizeof(OutT) == 2) {
                bf16x4 o = {(bf16_t)v0, (bf16_t)v1, (bf16_t)v2, (bf16_t)v3};
                *(bf16x4*)dst = o;
            } else {
                float4 o = {v0, v1, v2, v3};
                *(float4*)dst = o;
            }
        }
    }
}

// ---------------------------------------------------------------------------
// MFMA attention, one block (4 waves) per (b,h), SWAPPED QK^T:
//   sc[c] = mfma(K_frag, Q_frag)  ->  lane(ln,ko) reg r holds
//   S^T[m = 16c + ko*4 + r][q = ln].
// Softmax over keys = 52 in-lane values + shfl_xor(16,32). P never touches
// LDS: the lane's own 8 probabilities form the PV B-fragment under the
// k-slot permutation kk(m) = (m&~31) + ((m&15)>>2)*8 + ((m>>4)&1)*4 + (m&3),
// with V^T staged in the same permuted layout. No barriers in the t-loop.
// ---------------------------------------------------------------------------
__global__ __launch_bounds__(256) void attn_mfma(const bf16_t* __restrict__ qkv,
                                                 const bf16_t* __restrict__ biasT,
                                                 bf16_t* __restrict__ out) {
    const int b = blockIdx.x / H_;
    const int h = blockIdx.x % H_;
    __shared__ __align__(16) bf16_t Ks[NP_][32];     // 13312 B
    __shared__ __align__(16) bf16_t Vt[VD_][VSTR_];  // 16896 B (kslot-permuted V^T)
    const int tid  = threadIdx.x;
    const int lane = tid & 63;
    const int wv   = tid >> 6;
    const int ln   = lane & 15;
    const int ko   = lane >> 4;

    // --- stage K via global_load_lds (13 chunks of 16 rows; source row clamped
    // so pad rows hold valid-but-ignored data, killed by -1e30 bias) ---
    {
        const int rsub = lane >> 2;
        const int col  = (lane & 3) * 8;
        for (int c = wv; c < 13; c += 4) {
            const int row  = c * 16 + rsub;
            const int srow = min(row, N_ - 1);
            gl2lds(qkv + ((size_t)(b * N_ + srow) * H_ + h) * 96 + KD_ + col,
                   &Ks[row][col]);
        }
    }
    // --- stage V^T permuted: key m -> column kk(m); m in [196,224) -> zeros ---
    if (tid < 224) {
        const int m  = tid;
        const int kk = (m & ~31) + ((m & 15) >> 2) * 8 + ((m >> 4) & 1) * 4 + (m & 3);
        const bf16_t* src = qkv + ((size_t)(b * N_ + min(m, N_ - 1)) * H_ + h) * 96 + 2 * KD_;
        #pragma unroll
        for (int c4 = 0; c4 < 4; c4++) {
            bf16x8 v8 = {bf16_t(0), bf16_t(0), bf16_t(0), bf16_t(0),
                         bf16_t(0), bf16_t(0), bf16_t(0), bf16_t(0)};
            if (m < N_) v8 = *(const bf16x8*)(src + c4 * 8);
            #pragma unroll
            for (int j = 0; j < 8; j++) Vt[c4 * 8 + j][kk] = v8[j];
        }
    }
    __syncthreads();

    // hoist K fragments into registers (reused across all t-tiles)
    bf16x8 kf[13];
    #pragma unroll
    for (int c = 0; c < 13; c++)
        kf[c] = *(const bf16x8*)&Ks[c * 16 + ln][ko * 8];

    for (int t = wv; t < 13; t += 4) {
        const int q    = t * 16 + ln;
        const int qrow = min(q, N_ - 1);
        const bf16x8 qf =
            *(const bf16x8*)(qkv + ((size_t)(b * N_ + qrow) * H_ + h) * 96 + ko * 8);

        f32x4 sc[13];
        __builtin_amdgcn_s_setprio(1);
        #pragma unroll
        for (int c = 0; c < 13; c++) {
            f32x4 z = {0.f, 0.f, 0.f, 0.f};
            sc[c] = mfma16(kf[c], qf, z);    // S^T
        }
        __builtin_amdgcn_s_setprio(0);

        // scale + bias (transposed layout: coalesced over ln) + max over keys
        const bf16_t* bT = biasT + ((size_t)(h * NP_) + ko * 4) * NP_ + t * 16 + ln;
        float mx = -1e30f;
        #pragma unroll
        for (int c = 0; c < 13; c++)
            #pragma unroll
            for (int r = 0; r < 4; r++) {
                const float s = sc[c][r] * SCALE_ + (float)bT[(c * 16 + r) * NP_];
                sc[c][r] = s;
                mx = fmaxf(mx, s);
            }
        mx = fmaxf(mx, __shfl_xor(mx, 16));
        mx = fmaxf(mx, __shfl_xor(mx, 32));
        float sum = 0.f;
        #pragma unroll
        for (int c = 0; c < 13; c++)
            #pragma unroll
            for (int r = 0; r < 4; r++) {
                const float p = __expf(sc[c][r] - mx);
                sc[c][r] = p;
                sum += p;
            }
        sum += __shfl_xor(sum, 16);
        sum += __shfl_xor(sum, 32);
        const float inv = 1.f / sum;

        // PV: O^T = V^T @ P^T, 7 k-groups of 32 permuted key slots.
        // B-fragment = the lane's own probabilities (pure register pack).
        f32x4 o0 = {0.f, 0.f, 0.f, 0.f};
        f32x4 o1 = {0.f, 0.f, 0.f, 0.f};
        __builtin_amdgcn_s_setprio(1);
        #pragma unroll
        for (int g = 0; g < 7; g++) {
            bf16x8 pf;
            #pragma unroll
            for (int jj = 0; jj < 4; jj++) pf[jj] = (bf16_t)sc[2 * g][jj];
            if (g < 6) {
                #pragma unroll
                for (int jj = 0; jj < 4; jj++) pf[4 + jj] = (bf16_t)sc[2 * g + 1][jj];
            } else {
                pf[4] = bf16_t(0); pf[5] = bf16_t(0);
                pf[6] = bf16_t(0); pf[7] = bf16_t(0);
            }
            const bf16x8 v0 = *(const bf16x8*)&Vt[ln][g * 32 + ko * 8];
            const bf16x8 v1 = *(const bf16x8*)&Vt[16 + ln][g * 32 + ko * 8];
            o0 = mfma16(v0, pf, o0);
            o1 = mfma16(v1, pf, o1);
        }
        __builtin_amdgcn_s_setprio(0);

        // lane holds O^T[v = ko*4 + r][q]: 4 consecutive v -> bf16x4 stores
        if (q < N_) {
            bf16_t* dst = out + (size_t)(b * N_ + q) * DIM_ + h * VD_ + ko * 4;
            bf16x4 oa = {(bf16_t)(o0[0] * inv), (bf16_t)(o0[1] * inv),
                         (bf16_t)(o0[2] * inv), (bf16_t)(o0[3] * inv)};
            bf16x4 ob = {(bf16_t)(o1[0] * inv), (bf16_t)(o1[1] * inv),
                         (bf16_t)(o1[2] * inv), (bf16_t)(o1[3] * inv)};
            *(bf16x4*)dst = oa;
            *(bf16x4*)(dst + 16) = ob;
        }
    }
}

// ---------------------------------------------------------------------------
extern "C" void kernel_launch(void* const* d_in, const int* in_sizes, int n_in,
                              void* d_out, int out_size, void* d_ws, size_t ws_size,
                              hipStream_t stream) {
    const float* x        = (const float*)d_in[0];
    const float* norm_w   = (const float*)d_in[1];
    const float* norm_b   = (const float*)d_in[2];
    const float* qkv_w    = (const float*)d_in[3];
    const float* qkv_b    = (const float*)d_in[4];
    const float* att_bias = (const float*)d_in[5];
    const float* proj_w   = (const float*)d_in[6];
    const float* proj_b   = (const float*)d_in[7];
    const int*   bias_idx = (const int*)d_in[8];
    float* out = (float*)d_out;

    char* ws = (char*)d_ws;
    size_t off = 0;
    bf16_t* xn       = (bf16_t*)(ws + off); off += (size_t)ROWS_ * DIM_ * 2;
    bf16_t* qkvbuf   = (bf16_t*)(ws + off); off += (size_t)ROWS_ * F_ * 2;
    bf16_t* attn_out = (bf16_t*)(ws + off); off += (size_t)ROWS_ * DIM_ * 2;
    bf16_t* biasT    = (bf16_t*)(ws + off); off += (size_t)H_ * NP_ * NP_ * 2;
    bf16_t* wq_bf    = (bf16_t*)(ws + off); off += (size_t)F_ * DIM_ * 2;
    bf16_t* wp_bf    = (bf16_t*)(ws + off); off += (size_t)DIM_ * DIM_ * 2;

    cvt_w<<<(F_ * DIM_) / 1024, 256, 0, stream>>>(qkv_w, wq_bf);
    cvt_w<<<(DIM_ * DIM_) / 1024, 256, 0, stream>>>(proj_w, wp_bf);
    ln_kernel<<<ROWS_ / 4, 256, 0, stream>>>(x, norm_w, norm_b, xn);
    bias_gather<<<(H_ * NP_ * NP_ + 255) / 256, 256, 0, stream>>>(att_bias, bias_idx, biasT);
    gemm_mfma<bf16_t><<<dim3(ROWS_ / 128, F_ / 128), 256, 0, stream>>>(
        xn, wq_bf, qkv_b, qkvbuf, ROWS_, F_, DIM_);
    attn_mfma<<<B_ * H_, 256, 0, stream>>>(qkvbuf, biasT, attn_out);
    gemm_mfma<float><<<dim3(ROWS_ / 128, DIM_ / 128), 256, 0, stream>>>(
        attn_out, wp_bf, proj_b, out, ROWS_, DIM_, DIM_);
}